// Round 4
// baseline (154.022 us; speedup 1.0000x reference)
//
#include <hip/hip_runtime.h>
#include <math.h>

// BoundaryLoss: out = mean |sigmoid(logits) - gt| * EDT_bg(gt)
// dist==0 exactly at gt==1  ->  |p-t|*dist == p*dist: targets only feed the
// fg bitmask.
// SINGLE dispatch, producer/consumer handoff through L2 (no grid.sync):
//   - producer: each block packs its own 16-row band (192 u32 words) with
//     plain coalesced stores, then threadfence + one tagged flag atomicExch.
//     (flag carries MAGIC tag in high word: poison-safe, self-validating)
//   - consumer: poll 24 band flags (1 per lane-group, every wave covers all),
//     barrier, then gather full image mask via independent pipelined 8B
//     agent-scope atomic loads (coherent-point reads: XCD-safe).
//   - Phase 1: clz/ffs exact nearest-fg row distance per column
//   - Phase 2: exact vertical envelope (early exit) + fused sigmoid*dist,
//     logits prefetched into registers at kernel start (issue-early).
//   - hierarchical tagged reduce: block partial -> per-image aggregator (24)
//     -> block 0 (16 image sums) -> plain store to out. No pre-zeroing.
// Deadlock-free: flags are set unconditionally BEFORE any poll (DAG), and
// all 384 blocks are co-resident anyway (32.3KB LDS, 2 blk/CU cap -> 512).

#define BB 16
#define HH 384
#define WW 384
#define WPR 12                 // u32 words per row
#define WPRP 13                // padded LDS stride (coprime 32: conflict-free)
#define SW 16                  // stripe width
#define NBLK (WW / SW)         // 24 stripes per image == 24 row-bands
#define RPB (HH / NBLK)        // 16 rows packed per producer block
#define THREADS 512
#define NBLOCKS (BB * NBLK)    // 384
#define BIGD 768
#define WORDS_PER_IMG (HH * WPR)          // 4608
#define PAIRS_PER_IMG (WORDS_PER_IMG / 2) // 2304
#define WPB (RPB * WPR)                   // 192 words produced per block
// ws layout in 8-byte slots:
#define FLAG_BASE ((BB * WORDS_PER_IMG) / 2)   // 36864: after u32 mask area
#define PART_BASE (FLAG_BASE + NBLOCKS)        // 37248
#define ISUM_BASE (PART_BASE + NBLOCKS)        // 37632
#define MAGA 0x9E3779B9u
#define TAG64 (((unsigned long long)MAGA) << 32)

__device__ __forceinline__ int blk_of(int bb, int st) {
  // inverse of the XCD swizzle: image bb, band st -> blockIdx
  return (bb >> 1) + 8 * ((bb & 1) * NBLK + st);
}

__device__ __forceinline__ float poll_tagged(unsigned long long* slot) {
  unsigned long long a =
      __hip_atomic_load(slot, __ATOMIC_RELAXED, __HIP_MEMORY_SCOPE_AGENT);
  while ((unsigned)(a >> 32) != MAGA) {
    __builtin_amdgcn_s_sleep(2);
    a = __hip_atomic_load(slot, __ATOMIC_RELAXED, __HIP_MEMORY_SCOPE_AGENT);
  }
  return __uint_as_float((unsigned)a);
}

__global__ __launch_bounds__(THREADS, 2) void boundary_fused(
    const float* __restrict__ logits, const int* __restrict__ gt,
    unsigned long long* ws, float* __restrict__ out) {
  // XCD swizzle: blockIdx%8 == XCD (round-robin dispatch). 2 images per XCD,
  // all 24 blocks of an image on the same XCD -> mask handoff stays in L2.
  const int p = blockIdx.x;
  const int xcd = p & 7;
  const int slot = p >> 3;                  // 0..47
  const int sub = (slot >= NBLK) ? 1 : 0;
  const int b = xcd * 2 + sub;              // image 0..15
  const int st = slot - sub * NBLK;         // stripe / band index 0..23
  const int j0 = st * SW;                   // stripe origin column
  const int r0 = st * RPB;                  // producer band origin row
  const float* __restrict__ lg = logits + b * HH * WW;
  const int* __restrict__ gimg = gt + b * HH * WW;
  unsigned* mimg32 = (unsigned*)ws + b * WORDS_PER_IMG;
  unsigned long long* mimg64 = ws + (size_t)b * PAIRS_PER_IMG;

  __shared__ unsigned m_s[HH * WPRP];       // 19968 B
  __shared__ unsigned short g_s[HH * SW];   // 12288 B
  __shared__ float red[THREADS / 64];

  // ---- Prefetch logits stripe into registers (consumed in Phase 2) ----
  float4 xf[3];
#pragma unroll
  for (int t = 0; t < 3; ++t) {
    const int s = threadIdx.x + t * THREADS;        // < 1536
    const int i = s >> 2;
    const int jj = (s & 3) * 4;
    xf[t] = *(const float4*)(lg + i * WW + j0 + jj);
  }

  // ---- Producer: pack own 16-row band, plain coalesced stores ----
  if (threadIdx.x < WPB) {
    const int q = threadIdx.x;              // 0..191; word index r0*WPR + q
    const int4* __restrict__ g4 = (const int4*)(gimg + r0 * WW + q * 32);
    unsigned word = 0;
#pragma unroll
    for (int k = 0; k < 8; ++k) {
      const int4 v = g4[k];
      word |= ((unsigned)(v.x != 0)) << (k * 4);
      word |= ((unsigned)(v.y != 0)) << (k * 4 + 1);
      word |= ((unsigned)(v.z != 0)) << (k * 4 + 2);
      word |= ((unsigned)(v.w != 0)) << (k * 4 + 3);
    }
    mimg32[r0 * WPR + q] = word;            // contiguous 768B per block
  }
  __threadfence();                          // storers: push to coherent point
  __syncthreads();
  if (threadIdx.x == 0) {                   // band complete -> tagged flag
    atomicExch(ws + FLAG_BASE + p, TAG64 | 1ULL);
  }

  // ---- Consumer: wait for all 24 bands (every wave polls all flags) ----
  {
    const int f = threadIdx.x & 31;
    if (f < NBLK) (void)poll_tagged(ws + FLAG_BASE + blk_of(b, f));
  }
  __syncthreads();

  // ---- Gather full image mask: independent pipelined 8B atomic loads ----
  for (int idx = threadIdx.x; idx < PAIRS_PER_IMG; idx += THREADS) {  // <=5
    const unsigned long long v =
        __hip_atomic_load(mimg64 + idx, __ATOMIC_RELAXED, __HIP_MEMORY_SCOPE_AGENT);
    const int wp = idx * 2;
    const int row = wp / WPR;
    const int w = wp - row * WPR;           // even: pair never crosses a row
    unsigned* dst = m_s + row * WPRP + w;
    dst[0] = (unsigned)v;
    dst[1] = (unsigned)(v >> 32);
  }
  __syncthreads();

  // ---- Phase 1: exact nearest-fg row distance, 4 cols/thread ----
#pragma unroll
  for (int t = 0; t < 3; ++t) {             // 1536 = 512*3
    const int s = threadIdx.x + t * THREADS;
    const int i = s >> 2;
    const int jj = (s & 3) * 4;
    const int j = j0 + jj;                  // multiple of 4: 4 bits in one word
    const unsigned* __restrict__ mr = m_s + i * WPRP;
    const int w = j >> 5;
    const int bpos = j & 31;                // 0,4,...,28
    const unsigned cur = mr[w];

    int jL = -0x40000;
    if ((cur & (0xFFFFFFFFu >> (31 - bpos))) == 0u) {
      for (int ww = w - 1; ww >= 0; --ww) {
        const unsigned x = mr[ww];
        if (x) { jL = ww * 32 + 31 - __clz(x); break; }
      }
    }
    int jR = 0x40000;
    if ((cur & (0xFFFFFFFFu << (bpos + 3))) == 0u) {
      for (int ww = w + 1; ww < WPR; ++ww) {
        const unsigned x = mr[ww];
        if (x) { jR = ww * 32 + __ffs(x) - 1; break; }
      }
    }
    unsigned short g4[4];
#pragma unroll
    for (int c = 0; c < 4; ++c) {
      const int bc = bpos + c;
      const int jc = j + c;
      const unsigned lm = cur & (0xFFFFFFFFu >> (31 - bc));
      const unsigned rm = cur & (0xFFFFFFFFu << bc);
      const int dl = lm ? (bc - (31 - __clz(lm))) : (jc - jL);
      const int dr = rm ? ((__ffs(rm) - 1) - bc) : (jR - jc);
      g4[c] = (unsigned short)min(min(dl, dr), BIGD);
    }
    ushort4 gv; gv.x = g4[0]; gv.y = g4[1]; gv.z = g4[2]; gv.w = g4[3];
    *(ushort4*)(g_s + i * SW + jj) = gv;
  }
  __syncthreads();

  // ---- Phase 2: exact vertical envelope (early exit r*r >= best) + loss ----
  float acc = 0.0f;
#pragma unroll
  for (int t = 0; t < 3; ++t) {
    const int s = threadIdx.x + t * THREADS;
    const int i = s >> 2;
    const int jj = (s & 3) * 4;
    const ushort4 gv = *(const ushort4*)(g_s + i * SW + jj);
    const float4 x4 = xf[t];
    const int gg[4] = {gv.x, gv.y, gv.z, gv.w};
    const float xs[4] = {x4.x, x4.y, x4.z, x4.w};
#pragma unroll
    for (int c = 0; c < 4; ++c) {
      int best = gg[c] * gg[c];
      for (int r = 1; r * r < best; ++r) {
        const int im = i - r, ip = i + r;
        if (im >= 0) { const int v = g_s[im * SW + jj + c]; best = min(best, r * r + v * v); }
        if (ip < HH) { const int v = g_s[ip * SW + jj + c]; best = min(best, r * r + v * v); }
      }
      const float dist = __builtin_amdgcn_sqrtf((float)best);     // rel ~1e-7
      const float p2 = __builtin_amdgcn_rcpf(1.0f + __expf(-xs[c])); // ~2.5e-7
      acc += p2 * dist;                       // == |p-t|*dist (dist=0 at fg)
    }
  }

  // ---- Block reduction -> publish tagged partial ----
  for (int off = 32; off > 0; off >>= 1) acc += __shfl_down(acc, off, 64);
  const int lane = threadIdx.x & 63;
  const int wid = threadIdx.x >> 6;
  if (lane == 0) red[wid] = acc;
  __syncthreads();
  if (threadIdx.x == 0) {
    float ssum = 0.0f;
    for (int w = 0; w < THREADS / 64; ++w) ssum += red[w];
    atomicExch(ws + PART_BASE + p,
               TAG64 | (unsigned long long)__float_as_uint(ssum));
  }

  // ---- Per-image aggregator (band 0 of each image): 24 partials -> 1 ----
  if (st == 0 && threadIdx.x < 64) {
    const int t = threadIdx.x;
    float v = (t < NBLK) ? poll_tagged(ws + PART_BASE + blk_of(b, t)) : 0.0f;
    for (int off = 32; off > 0; off >>= 1) v += __shfl_down(v, off, 64);
    if (t == 0) {
      atomicExch(ws + ISUM_BASE + b,
                 TAG64 | (unsigned long long)__float_as_uint(v));
    }
  }

  // ---- Final: block 0 sums 16 image sums, stores out ----
  if (p == 0 && threadIdx.x < 64) {
    const int t = threadIdx.x;
    float v = (t < BB) ? poll_tagged(ws + ISUM_BASE + t) : 0.0f;
    for (int off = 32; off > 0; off >>= 1) v += __shfl_down(v, off, 64);
    if (t == 0) out[0] = v * (1.0f / (float)(BB * HH * WW));
  }
}

extern "C" void kernel_launch(void* const* d_in, const int* in_sizes, int n_in,
                              void* d_out, int out_size, void* d_ws, size_t ws_size,
                              hipStream_t stream) {
  const float* logits = (const float*)d_in[0];
  const int* targets = (const int*)d_in[1];
  float* out = (float*)d_out;
  unsigned long long* ws = (unsigned long long*)d_ws;  // 301,184 B used

  boundary_fused<<<NBLOCKS, THREADS, 0, stream>>>(logits, targets, ws, out);
}

// Round 5
// 79.306 us; speedup vs baseline: 1.9421x; 1.9421x over previous
//
#include <hip/hip_runtime.h>
#include <math.h>

// BoundaryLoss: out = mean |sigmoid(logits) - gt| * EDT_bg(gt)
// dist==0 exactly at gt==1  ->  |p-t|*dist == p*dist: targets only feed the
// fg bitmask.
// Two-kernel verified structure (single-dispatch handoffs all lost: R1-R4).
// K1 pack: 8 px/thread -> fg byte -> LDS -> u32 word stores (+ zero d_out).
// K2 main: 768 blocks (2 per 16-col stripe, split by row-half) for 3 blk/CU:
//          full-column P1 (cheap, duplicated), half-rows P2 (expensive),
//          logits half prefetched to registers at kernel start (overlaps
//          mask staging + P1), fused sigmoid*dist reduce, one atomic/block.

#define BB 16
#define HH 384
#define WW 384
#define WPR 12                 // u32 words per row
#define WPRP 13                // padded LDS stride (coprime 32: conflict-free)
#define SW 16                  // stripe width
#define NBLK (WW / SW)         // 24 stripes per image
#define HALF (HH / 2)          // 192 rows of P2 per block
#define THREADS 384            // 6 waves
#define NBLOCKS (BB * NBLK * 2)  // 768
#define PTHREADS 256
#define BIGD 768

__global__ __launch_bounds__(PTHREADS) void pack_kernel(
    const int* __restrict__ gt, unsigned* __restrict__ mask,
    float* __restrict__ out) {
  __shared__ unsigned char s_byte[PTHREADS];
  const int base = blockIdx.x * PTHREADS * 8;        // 2048 px per block
  const int4* __restrict__ g4 = (const int4*)(gt + base);
  const int4 a = g4[threadIdx.x * 2];
  const int4 b = g4[threadIdx.x * 2 + 1];
  unsigned byte = (a.x != 0) | ((a.y != 0) << 1) | ((a.z != 0) << 2) |
                  ((a.w != 0) << 3) | ((b.x != 0) << 4) | ((b.y != 0) << 5) |
                  ((b.z != 0) << 6) | ((b.w != 0) << 7);
  s_byte[threadIdx.x] = (unsigned char)byte;
  __syncthreads();
  if (threadIdx.x < PTHREADS / 4) {                  // 64 word stores
    mask[(base >> 5) + threadIdx.x] = *(const unsigned*)(s_byte + threadIdx.x * 4);
  }
  if (blockIdx.x == 0 && threadIdx.x == 0) out[0] = 0.0f;
}

__global__ __launch_bounds__(THREADS) void boundary_loss_kernel(
    const float* __restrict__ logits, const unsigned* __restrict__ mask,
    float* __restrict__ out) {
  const int blk = blockIdx.x;
  const int b = blk / (NBLK * 2);
  const int r2 = blk - b * (NBLK * 2);
  const int st = r2 >> 1;                   // stripe 0..23
  const int h = r2 & 1;                     // row-half 0..1
  const int j0 = st * SW;
  const int i0 = h * HALF;                  // P2 row origin
  const float* __restrict__ lg = logits + b * HH * WW;

  __shared__ unsigned m_s[HH * WPRP];       // 19968 B
  __shared__ unsigned short g_s[HH * SW];   // 12288 B
  __shared__ float red[THREADS / 64];

  // ---- Prefetch this half's logits stripe into registers (use-late) ----
  float4 xf[2];
#pragma unroll
  for (int t = 0; t < 2; ++t) {
    const int s = threadIdx.x + t * THREADS;        // < 768
    const int i = i0 + (s >> 2);
    const int jj = (s & 3) * 4;
    xf[t] = *(const float4*)(lg + i * WW + j0 + jj);
  }

  // ---- stage fg bitmask: uint4 global loads, scalar LDS writes (padded) ----
  const uint4* __restrict__ gm4 = (const uint4*)(mask + b * HH * WPR);
#pragma unroll
  for (int t = 0; t < 3; ++t) {             // 1152 = 384*3
    const int s = threadIdx.x + t * THREADS;
    const uint4 v = gm4[s];
    const int row = s / 3;
    const int w0 = (s - row * 3) * 4;
    unsigned* dst = m_s + row * WPRP + w0;
    dst[0] = v.x; dst[1] = v.y; dst[2] = v.z; dst[3] = v.w;
  }
  __syncthreads();

  // ---- Phase 1: exact nearest-fg row distance, FULL column, 4 cols/thr ----
#pragma unroll
  for (int t = 0; t < 4; ++t) {             // 1536 = 384*4
    const int s = threadIdx.x + t * THREADS;
    const int i = s >> 2;
    const int jj = (s & 3) * 4;
    const int j = j0 + jj;                  // multiple of 4: 4 bits in one word
    const unsigned* __restrict__ mr = m_s + i * WPRP;
    const int w = j >> 5;
    const int bpos = j & 31;                // 0,4,...,28
    const unsigned cur = mr[w];

    int jL = -0x40000;
    if ((cur & (0xFFFFFFFFu >> (31 - bpos))) == 0u) {
      for (int ww = w - 1; ww >= 0; --ww) {
        const unsigned x = mr[ww];
        if (x) { jL = ww * 32 + 31 - __clz(x); break; }
      }
    }
    int jR = 0x40000;
    if ((cur & (0xFFFFFFFFu << (bpos + 3))) == 0u) {
      for (int ww = w + 1; ww < WPR; ++ww) {
        const unsigned x = mr[ww];
        if (x) { jR = ww * 32 + __ffs(x) - 1; break; }
      }
    }
    unsigned short g4[4];
#pragma unroll
    for (int c = 0; c < 4; ++c) {
      const int bc = bpos + c;
      const int jc = j + c;
      const unsigned lm = cur & (0xFFFFFFFFu >> (31 - bc));
      const unsigned rm = cur & (0xFFFFFFFFu << bc);
      const int dl = lm ? (bc - (31 - __clz(lm))) : (jc - jL);
      const int dr = rm ? ((__ffs(rm) - 1) - bc) : (jR - jc);
      g4[c] = (unsigned short)min(min(dl, dr), BIGD);
    }
    ushort4 gv; gv.x = g4[0]; gv.y = g4[1]; gv.z = g4[2]; gv.w = g4[3];
    *(ushort4*)(g_s + i * SW + jj) = gv;
  }
  __syncthreads();

  // ---- Phase 2: exact vertical envelope, THIS HALF's rows only + loss ----
  float acc = 0.0f;
#pragma unroll
  for (int t = 0; t < 2; ++t) {             // 768 = 384*2 cell-groups
    const int s = threadIdx.x + t * THREADS;
    const int i = i0 + (s >> 2);
    const int jj = (s & 3) * 4;
    const ushort4 gv = *(const ushort4*)(g_s + i * SW + jj);
    const float4 x4 = xf[t];
    const int gg[4] = {gv.x, gv.y, gv.z, gv.w};
    const float xs[4] = {x4.x, x4.y, x4.z, x4.w};
#pragma unroll
    for (int c = 0; c < 4; ++c) {
      int best = gg[c] * gg[c];
      for (int r = 1; r * r < best; ++r) {
        const int im = i - r, ip = i + r;
        if (im >= 0) { const int v = g_s[im * SW + jj + c]; best = min(best, r * r + v * v); }
        if (ip < HH) { const int v = g_s[ip * SW + jj + c]; best = min(best, r * r + v * v); }
      }
      const float dist = __builtin_amdgcn_sqrtf((float)best);     // rel ~1e-7
      const float p = __builtin_amdgcn_rcpf(1.0f + __expf(-xs[c])); // ~2.5e-7
      acc += p * dist;                        // == |p-t|*dist (dist=0 at fg)
    }
  }

  // ---- Block reduction -> one fire-and-forget atomic per block ----
  for (int off = 32; off > 0; off >>= 1) acc += __shfl_down(acc, off, 64);
  const int lane = threadIdx.x & 63;
  const int wid = threadIdx.x >> 6;
  if (lane == 0) red[wid] = acc;
  __syncthreads();
  if (threadIdx.x == 0) {
    float ssum = 0.0f;
    for (int w = 0; w < THREADS / 64; ++w) ssum += red[w];
    atomicAdd(out, ssum * (1.0f / (float)(BB * HH * WW)));
  }
}

extern "C" void kernel_launch(void* const* d_in, const int* in_sizes, int n_in,
                              void* d_out, int out_size, void* d_ws, size_t ws_size,
                              hipStream_t stream) {
  const float* logits = (const float*)d_in[0];
  const int* targets = (const int*)d_in[1];
  float* out = (float*)d_out;
  unsigned* mask = (unsigned*)d_ws;       // 294912 B

  pack_kernel<<<(BB * HH * WW) / (PTHREADS * 8), PTHREADS, 0, stream>>>(targets, mask, out);
  boundary_loss_kernel<<<NBLOCKS, THREADS, 0, stream>>>(logits, mask, out);
}

// Round 6
// 78.114 us; speedup vs baseline: 1.9718x; 1.0153x over previous
//
#include <hip/hip_runtime.h>
#include <math.h>

// BoundaryLoss: out = mean |sigmoid(logits) - gt| * EDT_bg(gt)
// dist==0 exactly at gt==1  ->  |p-t|*dist == p*dist: targets only feed the
// fg bitmask.
// Two-kernel verified structure (R0 best = 76.5; all 1-dispatch handoffs and
// the 768-block split lost). This round: R0 config + logits register
// prefetch (issue-early/use-late) + fixed-trip unrolled phase loops.
// K1 pack: 8 px/thread -> fg byte -> LDS -> u32 word stores (+ zero d_out).
// K2 main: per 16-col stripe: bitmask -> LDS, clz/ffs exact row distances,
//          early-exit exact vertical envelope, fused sigmoid*dist reduce.

#define BB 16
#define HH 384
#define WW 384
#define WPR 12                 // u32 words per row
#define WPRP 13                // padded LDS stride (coprime 32: conflict-free)
#define SW 16                  // stripe width
#define NBLK (WW / SW)         // 24
#define THREADS 512
#define PTHREADS 256
#define BIGD 768

__global__ __launch_bounds__(PTHREADS) void pack_kernel(
    const int* __restrict__ gt, unsigned* __restrict__ mask,
    float* __restrict__ out) {
  __shared__ unsigned char s_byte[PTHREADS];
  const int base = blockIdx.x * PTHREADS * 8;        // 2048 px per block
  const int4* __restrict__ g4 = (const int4*)(gt + base);
  const int4 a = g4[threadIdx.x * 2];
  const int4 b = g4[threadIdx.x * 2 + 1];
  unsigned byte = (a.x != 0) | ((a.y != 0) << 1) | ((a.z != 0) << 2) |
                  ((a.w != 0) << 3) | ((b.x != 0) << 4) | ((b.y != 0) << 5) |
                  ((b.z != 0) << 6) | ((b.w != 0) << 7);
  s_byte[threadIdx.x] = (unsigned char)byte;
  __syncthreads();
  if (threadIdx.x < PTHREADS / 4) {                  // 64 word stores
    mask[(base >> 5) + threadIdx.x] = *(const unsigned*)(s_byte + threadIdx.x * 4);
  }
  if (blockIdx.x == 0 && threadIdx.x == 0) out[0] = 0.0f;
}

__global__ __launch_bounds__(THREADS) void boundary_loss_kernel(
    const float* __restrict__ logits, const unsigned* __restrict__ mask,
    float* __restrict__ out) {
  const int blk = blockIdx.x;
  const int b = blk / NBLK;
  const int j0 = (blk % NBLK) * SW;
  const float* __restrict__ lg = logits + b * HH * WW;

  __shared__ unsigned m_s[HH * WPRP];       // 19968 B
  __shared__ unsigned short g_s[HH * SW];   // 12288 B
  __shared__ float red[THREADS / 64];

  // ---- Prefetch logits stripe into registers (consumed in Phase 2):
  //      HBM latency hides under mask staging + Phase 1 ----
  float4 xf[3];
#pragma unroll
  for (int t = 0; t < 3; ++t) {
    const int s = threadIdx.x + t * THREADS;        // < 1536
    const int i = s >> 2;
    const int jj = (s & 3) * 4;
    xf[t] = *(const float4*)(lg + i * WW + j0 + jj);
  }

  // ---- stage fg bitmask: uint4 global loads, scalar LDS writes (padded) ----
  const uint4* __restrict__ gm4 = (const uint4*)(mask + b * HH * WPR);
#pragma unroll
  for (int t = 0; t < 3; ++t) {             // 1152 = 512*2 + 128
    const int s = threadIdx.x + t * THREADS;
    if (s < HH * WPR / 4) {
      const uint4 v = gm4[s];
      const int row = s / 3;
      const int w0 = (s - row * 3) * 4;
      unsigned* dst = m_s + row * WPRP + w0;
      dst[0] = v.x; dst[1] = v.y; dst[2] = v.z; dst[3] = v.w;
    }
  }
  __syncthreads();

  // ---- Phase 1: exact nearest-fg row distance, 4 cols/thread ----
#pragma unroll
  for (int t = 0; t < 3; ++t) {             // 1536 = 512*3
    const int s = threadIdx.x + t * THREADS;
    const int i = s >> 2;
    const int jj = (s & 3) * 4;
    const int j = j0 + jj;                  // multiple of 4: 4 bits in one word
    const unsigned* __restrict__ mr = m_s + i * WPRP;
    const int w = j >> 5;
    const int bpos = j & 31;                // 0,4,...,28
    const unsigned cur = mr[w];

    int jL = -0x40000;
    if ((cur & (0xFFFFFFFFu >> (31 - bpos))) == 0u) {
      for (int ww = w - 1; ww >= 0; --ww) {
        const unsigned x = mr[ww];
        if (x) { jL = ww * 32 + 31 - __clz(x); break; }
      }
    }
    int jR = 0x40000;
    if ((cur & (0xFFFFFFFFu << (bpos + 3))) == 0u) {
      for (int ww = w + 1; ww < WPR; ++ww) {
        const unsigned x = mr[ww];
        if (x) { jR = ww * 32 + __ffs(x) - 1; break; }
      }
    }
    unsigned short g4[4];
#pragma unroll
    for (int c = 0; c < 4; ++c) {
      const int bc = bpos + c;
      const int jc = j + c;
      const unsigned lm = cur & (0xFFFFFFFFu >> (31 - bc));
      const unsigned rm = cur & (0xFFFFFFFFu << bc);
      const int dl = lm ? (bc - (31 - __clz(lm))) : (jc - jL);
      const int dr = rm ? ((__ffs(rm) - 1) - bc) : (jR - jc);
      g4[c] = (unsigned short)min(min(dl, dr), BIGD);
    }
    ushort4 gv; gv.x = g4[0]; gv.y = g4[1]; gv.z = g4[2]; gv.w = g4[3];
    *(ushort4*)(g_s + i * SW + jj) = gv;
  }
  __syncthreads();

  // ---- Phase 2: exact vertical envelope (early exit r*r >= best) + loss ----
  float acc = 0.0f;
#pragma unroll
  for (int t = 0; t < 3; ++t) {
    const int s = threadIdx.x + t * THREADS;
    const int i = s >> 2;
    const int jj = (s & 3) * 4;
    const ushort4 gv = *(const ushort4*)(g_s + i * SW + jj);
    const float4 x4 = xf[t];
    const int gg[4] = {gv.x, gv.y, gv.z, gv.w};
    const float xs[4] = {x4.x, x4.y, x4.z, x4.w};
#pragma unroll
    for (int c = 0; c < 4; ++c) {
      int best = gg[c] * gg[c];
      for (int r = 1; r * r < best; ++r) {
        const int im = i - r, ip = i + r;
        if (im >= 0) { const int v = g_s[im * SW + jj + c]; best = min(best, r * r + v * v); }
        if (ip < HH) { const int v = g_s[ip * SW + jj + c]; best = min(best, r * r + v * v); }
      }
      const float dist = __builtin_amdgcn_sqrtf((float)best);     // rel ~1e-7
      const float p = __builtin_amdgcn_rcpf(1.0f + __expf(-xs[c])); // ~2.5e-7
      acc += p * dist;                        // == |p-t|*dist (dist=0 at fg)
    }
  }

  // ---- Block reduction -> one fire-and-forget atomic per block ----
  for (int off = 32; off > 0; off >>= 1) acc += __shfl_down(acc, off, 64);
  const int lane = threadIdx.x & 63;
  const int wid = threadIdx.x >> 6;
  if (lane == 0) red[wid] = acc;
  __syncthreads();
  if (threadIdx.x == 0) {
    float ssum = 0.0f;
    for (int w = 0; w < THREADS / 64; ++w) ssum += red[w];
    atomicAdd(out, ssum * (1.0f / (float)(BB * HH * WW)));
  }
}

extern "C" void kernel_launch(void* const* d_in, const int* in_sizes, int n_in,
                              void* d_out, int out_size, void* d_ws, size_t ws_size,
                              hipStream_t stream) {
  const float* logits = (const float*)d_in[0];
  const int* targets = (const int*)d_in[1];
  float* out = (float*)d_out;
  unsigned* mask = (unsigned*)d_ws;       // 294912 B

  pack_kernel<<<(BB * HH * WW) / (PTHREADS * 8), PTHREADS, 0, stream>>>(targets, mask, out);
  boundary_loss_kernel<<<BB * NBLK, THREADS, 0, stream>>>(logits, mask, out);
}